// Round 5
// baseline (596.458 us; speedup 1.0000x reference)
//
#include <hip/hip_runtime.h>
#include <hip/hip_bf16.h>

typedef __bf16 v8bf16 __attribute__((ext_vector_type(8)));
typedef float  v4f32  __attribute__((ext_vector_type(4)));
typedef unsigned short ushort8v __attribute__((ext_vector_type(8)));

static __device__ __forceinline__ float leaky(float v) { return v >= 0.0f ? v : 0.01f * v; }
static __device__ __forceinline__ float bfbits2f(unsigned short b) {
    union { unsigned u; float f; } c; c.u = ((unsigned)b) << 16; return c.f;
}
static __device__ __forceinline__ unsigned short f2bfbits(float f) {
    __hip_bfloat16 h = __float2bfloat16(f);
    unsigned short s; __builtin_memcpy(&s, &h, 2); return s;
}

// ---------------------------------------------------------------------------
// CSR build constants: buckets of 256 dst nodes, fixed-capacity padded
// regions (mean load 8184, BCAP=16384 ~ 90 sigma for uniform random dst).
// ebuck word: src | (dst&255)<<20  (needs NN < 2^20).
// csr uses the SAME padded layout (bucket k at k*BCAP) -> no global scan.
// ---------------------------------------------------------------------------
constexpr int EPB  = 6400;
constexpr int BCAP = 16384;

// Proportional interleave: spread nA "A-role" blocks uniformly over tot bids
// so each CU's resident set mixes latency-bound and MFMA blocks.
static __device__ __forceinline__ bool role_split(int bid, int nA, int tot,
                                                  int& idxA, int& idxB) {
    const long long s0 = (long long)bid * nA / tot;
    const long long s1 = (long long)(bid + 1) * nA / tot;
    if (s1 > s0) { idxA = (int)s0; idxB = 0; return true; }
    idxA = 0; idxB = bid - (int)s0; return false;
}

// ---------------------------------------------------------------------------
// L1: fused weight prep + bcur zero.
// ---------------------------------------------------------------------------
__global__ __launch_bounds__(256) void prep_all(
    const float* __restrict__ W1, const float* __restrict__ W2,
    const float* __restrict__ Wg1, const float* __restrict__ Wg2,
    __hip_bfloat16* __restrict__ W1f, __hip_bfloat16* __restrict__ W2t,
    __hip_bfloat16* __restrict__ Wg1t, __hip_bfloat16* __restrict__ Wg2t,
    unsigned* __restrict__ bcur, int DIN, int DH, int DO, int NB) {
    const int fragTotal  = DIN * DH;
    const int fragBlocks = (fragTotal + 255) / 256;
    const int n2 = DH * DO, ng = DO * DO;
    const int smallTotal  = n2 + 2 * ng;
    const int smallBlocks = (smallTotal + 255) / 256;
    const int bid = blockIdx.x;
    if (bid < fragBlocks) {
        int tid = bid * 256 + threadIdx.x;
        if (tid >= fragTotal) return;
        int j = tid & 7, l = (tid >> 3) & 63, G = tid >> 9;
        int m = l & 15, q = l >> 4;
        int t = G & 7, kk = G >> 3;
        int n = t * 16 + m;
        int k = kk * 32 + q * 8 + j;
        W1f[tid] = __float2bfloat16(W1[k * DH + n]);
    } else if (bid < fragBlocks + smallBlocks) {
        int i = (bid - fragBlocks) * 256 + threadIdx.x;
        if (i < n2) {
            int r = i / DO, c = i % DO;
            W2t[c * DH + r] = __float2bfloat16(W2[i]);
        } else if (i < n2 + ng) {
            int j = i - n2; int r = j / DO, c = j % DO;
            Wg1t[c * DO + r] = __float2bfloat16(Wg1[j]);
        } else if (i < smallTotal) {
            int j = i - n2 - ng; int r = j / DO, c = j % DO;
            Wg2t[c * DO + r] = __float2bfloat16(Wg2[j]);
        }
    } else {
        int i = (bid - fragBlocks - smallBlocks) * 256 + threadIdx.x;
        if (i < NB) bcur[i] = 0u;
    }
}

// ---------------------------------------------------------------------------
// Scatter body (512 threads): partition edges into per-bucket regions.
// dst values held in registers between phases (one global read of dst).
// ---------------------------------------------------------------------------
struct ScatterSmem {
    unsigned stg[EPB];
    unsigned hist[512], inc[512], cur[512], start[512];
};

static __device__ __forceinline__ void scatter_body(
    int bid, ScatterSmem& sm, const int* __restrict__ src, const int* __restrict__ dst,
    unsigned* __restrict__ bcur, unsigned* __restrict__ ebuck, int E, int NB) {
    const int tid = threadIdx.x;
    sm.hist[tid] = 0u;
    __syncthreads();
    const int beg = bid * EPB;
    const int end = min(beg + EPB, E);
    unsigned myd[13];
#pragma unroll
    for (int i = 0; i < 13; i++) {
        const int e = beg + tid + i * 512;
        if (e < end) {
            const unsigned d = (unsigned)dst[e];
            myd[i] = d;
            atomicAdd(&sm.hist[d >> 8], 1u);
        }
    }
    __syncthreads();
    const unsigned h = sm.hist[tid];
    sm.inc[tid] = h;
    __syncthreads();
    for (int off = 1; off < 512; off <<= 1) {
        unsigned t = (tid >= off) ? sm.inc[tid - off] : 0u;
        __syncthreads();
        sm.inc[tid] += t;
        __syncthreads();
    }
    sm.cur[tid] = sm.inc[tid] - h;
    if (tid < NB && h > 0u)
        sm.start[tid] = (unsigned)tid * BCAP + atomicAdd(&bcur[tid], h);
    __syncthreads();
#pragma unroll
    for (int i = 0; i < 13; i++) {
        const int e = beg + tid + i * 512;
        if (e < end) {
            const unsigned b = myd[i] >> 8;
            const unsigned r = atomicAdd(&sm.cur[b], 1u);
            sm.stg[r] = (unsigned)e;
        }
    }
    __syncthreads();
    const int cnt = end - beg;
    for (int s = tid; s < cnt; s += 512) {
        const unsigned e = sm.stg[s];
        const unsigned d = (unsigned)dst[e];   // L1-warm (25.6 KB window)
        const unsigned b = d >> 8;
        const unsigned excl = sm.inc[b] - sm.hist[b];
        const unsigned pos = sm.start[b] + ((unsigned)s - excl);
        ebuck[pos] = (unsigned)src[e] | ((d & 255u) << 20);
    }
}

// ---------------------------------------------------------------------------
// enc1 body, LDS-FREE (512 threads, 8 waves x 16 rows = 128 rows/block):
// C[M,128] = leaky(A[M,512]@W1 + b1), A fp32 (HBM stream), Bp
// fragment-ordered bf16 read DIRECTLY from global: W1f is 128 KB shared by
// all blocks -> L2-resident, so LDS staging + barriers are pure overhead.
// Barrier-free blocks free-run and overlap the scatter role's stalls.
// ---------------------------------------------------------------------------
static __device__ __forceinline__ void enc1_body(
    int bid, const float* __restrict__ A, const v8bf16* __restrict__ Bp,
    const float* __restrict__ bias, __hip_bfloat16* __restrict__ C, int M) {
    constexpr int K = 512;
    const int tid = threadIdx.x;
    const int wid = tid >> 6, lane = tid & 63;
    const int m = lane & 15, q = lane >> 4;
    const int row0 = bid * 128 + wid * 16;
    const int rowA = row0 + m;
    const int rowAc = rowA < M ? rowA : M - 1;
    const float* Ap = A + (size_t)rowAc * K + q * 8;

    v4f32 acc[8];
#pragma unroll
    for (int t = 0; t < 8; t++) acc[t] = (v4f32){0.f, 0.f, 0.f, 0.f};

    float4 ab[2][4];
    auto loadA = [&](int c, int par) {
#pragma unroll
        for (int j = 0; j < 4; j++)
            ab[par][j] = *reinterpret_cast<const float4*>(Ap + c * 64 + (j >> 1) * 32 + (j & 1) * 4);
    };

    loadA(0, 0);
#pragma unroll
    for (int c = 0; c < 8; c++) {
        if (c < 7) loadA(c + 1, (c + 1) & 1);
        const int par = c & 1;
#pragma unroll
        for (int kk2 = 0; kk2 < 2; kk2++) {
            float4 f0 = ab[par][kk2 * 2], f1 = ab[par][kk2 * 2 + 1];
            v8bf16 a = {(__bf16)f0.x, (__bf16)f0.y, (__bf16)f0.z, (__bf16)f0.w,
                        (__bf16)f1.x, (__bf16)f1.y, (__bf16)f1.z, (__bf16)f1.w};
#pragma unroll
            for (int t = 0; t < 8; t++) {
                v8bf16 b = Bp[(size_t)(c * 16 + kk2 * 8 + t) * 64 + lane];  // L2-hot, 1KB/wave coalesced
                acc[t] = __builtin_amdgcn_mfma_f32_16x16x32_bf16(a, b, acc[t], 0, 0, 0);
            }
        }
    }

#pragma unroll
    for (int r = 0; r < 4; r++) {
        const int row = row0 + q * 4 + r;
        if (row >= M) continue;
#pragma unroll
        for (int t = 0; t < 8; t++) {
            const int col = t * 16 + m;
            C[(size_t)row * 128 + col] = __float2bfloat16(leaky(acc[t][r] + bias[col]));
        }
    }
}

// ---------------------------------------------------------------------------
// L2: mega kernel = bucket_scatter || gemm_enc1, role-interleaved.
// ---------------------------------------------------------------------------
__global__ __launch_bounds__(512, 4) void mega_scatter_enc1(
    const int* __restrict__ src, const int* __restrict__ dst,
    unsigned* __restrict__ bcur, unsigned* __restrict__ ebuck, int E, int NB, int nScatter,
    const float* __restrict__ A, const v8bf16* __restrict__ Bp,
    const float* __restrict__ bias, __hip_bfloat16* __restrict__ C, int M) {
    __shared__ ScatterSmem sm;
    int ia, ib;
    if (role_split(blockIdx.x, nScatter, gridDim.x, ia, ib))
        scatter_body(ia, sm, src, dst, bcur, ebuck, E, NB);
    else
        enc1_body(ib, A, Bp, bias, C, M);
}

// ---------------------------------------------------------------------------
// Small GEMM body (bf16 A): C[M,N] = A[M,K]@B, Bt[N][K] bf16.
// MODE 0: C=bf16(leaky(AB+bias));  MODE 1: C=bf16((AB)*dinv[row])
// ---------------------------------------------------------------------------
template <int NT, int MODE>
static __device__ __forceinline__ void gemm_body(
    int bid, const __hip_bfloat16* __restrict__ A, const __hip_bfloat16* __restrict__ Bt,
    const float* __restrict__ bias, const float* __restrict__ dinv,
    __hip_bfloat16* __restrict__ Cbf, int M, int K) {
    const int wid  = threadIdx.x >> 6;
    const int lane = threadIdx.x & 63;
    const int row0 = (bid * 4 + wid) << 4;
    if (row0 >= M) return;
    const int m = lane & 15, q = lane >> 4;

    const __hip_bfloat16* Ab = A + (size_t)(row0 + m) * K + q * 8;

    v4f32 acc[NT];
#pragma unroll
    for (int t = 0; t < NT; t++) acc[t] = (v4f32){0.f, 0.f, 0.f, 0.f};

    for (int k0 = 0; k0 < K; k0 += 32) {
        v8bf16 a = *reinterpret_cast<const v8bf16*>(Ab + k0);
#pragma unroll
        for (int t = 0; t < NT; t++) {
            v8bf16 b = *reinterpret_cast<const v8bf16*>(Bt + (size_t)(t * 16 + m) * K + k0 + q * 8);
            acc[t] = __builtin_amdgcn_mfma_f32_16x16x32_bf16(a, b, acc[t], 0, 0, 0);
        }
    }

    const int N = NT * 16;
#pragma unroll
    for (int r = 0; r < 4; r++) {
        const int row = row0 + q * 4 + r;
        float di = (MODE == 1) ? dinv[row] : 1.0f;
#pragma unroll
        for (int t = 0; t < NT; t++) {
            const int col = t * 16 + m;
            float v = acc[t][r];
            if (MODE == 0) v = leaky(v + bias[col]);
            else           v *= di;
            Cbf[(size_t)row * N + col] = __float2bfloat16(v);
        }
    }
}

template <int NT, int MODE>
__global__ __launch_bounds__(256) void gemm_kernel(
    const __hip_bfloat16* __restrict__ A, const __hip_bfloat16* __restrict__ Bt,
    const float* __restrict__ bias, const float* __restrict__ dinv,
    __hip_bfloat16* __restrict__ Cbf, int M, int K) {
    gemm_body<NT, MODE>(blockIdx.x, A, Bt, bias, dinv, Cbf, M, K);
}

// ---------------------------------------------------------------------------
// bucket_csr body: one block per bucket; padded CSR layout (no scan).
// ---------------------------------------------------------------------------
static __device__ __forceinline__ void csr_body(
    int k, unsigned* hist, unsigned* cur, const unsigned* __restrict__ bcur,
    const unsigned* __restrict__ ebuck, uint2* __restrict__ rp2,
    float* __restrict__ dinv, int* __restrict__ csr, int NN) {
    const int tid = threadIdx.x;
    const unsigned cntb = bcur[k];
    const unsigned base = (unsigned)k * BCAP;
    const unsigned* eb = ebuck + base;
    hist[tid] = 0u;
    __syncthreads();
    for (unsigned e = tid; e < cntb; e += 256)
        atomicAdd(&hist[eb[e] >> 20], 1u);
    __syncthreads();
    const unsigned h = hist[tid];
    cur[tid] = h;
    __syncthreads();
    for (int off = 1; off < 256; off <<= 1) {
        unsigned t = (tid >= off) ? cur[tid - off] : 0u;
        __syncthreads();
        cur[tid] += t;
        __syncthreads();
    }
    const unsigned excl = cur[tid] - h;
    const int node = k * 256 + tid;
    if (node < NN) {
        rp2[node] = make_uint2(base + excl, base + excl + h);
        dinv[node] = rsqrtf((float)(h + 1u));  // +1 self-loop
    }
    __syncthreads();
    cur[tid] = excl;
    __syncthreads();
    for (unsigned e = tid; e < cntb; e += 256) {
        const unsigned pk = eb[e];
        const unsigned pos = base + atomicAdd(&cur[pk >> 20], 1u);
        csr[pos] = (int)(pk & 0xFFFFFu);
    }
}

// ---------------------------------------------------------------------------
// L3: mega kernel = bucket_csr || gemm_enc2, role-interleaved.
// ---------------------------------------------------------------------------
__global__ __launch_bounds__(256) void mega_csr_enc2(
    const unsigned* __restrict__ bcur, const unsigned* __restrict__ ebuck,
    uint2* __restrict__ rp2, float* __restrict__ dinv, int* __restrict__ csr,
    int NN, int nCsr,
    const __hip_bfloat16* __restrict__ A, const __hip_bfloat16* __restrict__ Bt,
    const float* __restrict__ bias, __hip_bfloat16* __restrict__ Cb, int M, int K) {
    __shared__ unsigned hist[256], cur[256];
    int ia, ib;
    if (role_split(blockIdx.x, nCsr, gridDim.x, ia, ib))
        csr_body(ia, hist, cur, bcur, ebuck, rp2, dinv, csr, NN);
    else
        gemm_body<4, 0>(ib, A, Bt, bias, nullptr, Cb, M, K);
}

// ---------------------------------------------------------------------------
// Fused CSR gather + GCN epilogue. One wave per dst node.
// 8 groups x 8 lanes, unroll-2 pipeline: 16 rows in flight per wave.
// ---------------------------------------------------------------------------
template <int HEAD>
__global__ __launch_bounds__(256) void gather_kernel(
    const uint2* __restrict__ rp2, const int* __restrict__ csr_src,
    const __hip_bfloat16* __restrict__ u, const float* __restrict__ dinv,
    const float* __restrict__ bias, __hip_bfloat16* __restrict__ out_bf,
    float* __restrict__ out_h, const float* __restrict__ Wc,
    const float* __restrict__ bc, float* __restrict__ out_logits, int n) {
    const int node = blockIdx.x * 4 + (threadIdx.x >> 6);
    if (node >= n) return;
    const int lane = threadIdx.x & 63;
    const int g = lane >> 3, t = lane & 7;  // 8 groups x 8 lanes
    const uint2 rp = rp2[node];
    const unsigned beg = rp.x, end = rp.y;

    float s[8];
#pragma unroll
    for (int j = 0; j < 8; j++) s[j] = 0.f;

    unsigned e = beg + g;
    bool hA = e < end, hB = e + 8 < end;
    int sA = hA ? csr_src[e] : 0;
    int sB = hB ? csr_src[e + 8] : 0;
    while (hA) {
        const unsigned en = e + 16;
        const bool hA2 = en < end, hB2 = en + 8 < end;
        const int sA2 = hA2 ? csr_src[en] : 0;
        const int sB2 = hB2 ? csr_src[en + 8] : 0;
        ushort8v wA = *reinterpret_cast<const ushort8v*>(u + (size_t)sA * 64 + t * 8);
        if (hB) {
            ushort8v wB = *reinterpret_cast<const ushort8v*>(u + (size_t)sB * 64 + t * 8);
#pragma unroll
            for (int j = 0; j < 8; j++) s[j] += bfbits2f(wA[j]) + bfbits2f(wB[j]);
        } else {
#pragma unroll
            for (int j = 0; j < 8; j++) s[j] += bfbits2f(wA[j]);
        }
        e = en; hA = hA2; hB = hB2; sA = sA2; sB = sB2;
    }
    // reduce across the 8 groups (lane bits 3,4,5)
#pragma unroll
    for (int j = 0; j < 8; j++) {
        s[j] += __shfl_xor(s[j], 8, 64);
        s[j] += __shfl_xor(s[j], 16, 64);
        s[j] += __shfl_xor(s[j], 32, 64);
    }

    // self-loop row
    ushort8v wsr = *reinterpret_cast<const ushort8v*>(u + (size_t)node * 64 + t * 8);
#pragma unroll
    for (int j = 0; j < 8; j++) s[j] += bfbits2f(wsr[j]);

    const float di = dinv[node];
    const float4 b0 = *reinterpret_cast<const float4*>(bias + t * 8);
    const float4 b1 = *reinterpret_cast<const float4*>(bias + t * 8 + 4);
    float f[8];
    f[0] = leaky(s[0] * di + b0.x); f[1] = leaky(s[1] * di + b0.y);
    f[2] = leaky(s[2] * di + b0.z); f[3] = leaky(s[3] * di + b0.w);
    f[4] = leaky(s[4] * di + b1.x); f[5] = leaky(s[5] * di + b1.y);
    f[6] = leaky(s[6] * di + b1.z); f[7] = leaky(s[7] * di + b1.w);

    if (HEAD == 0) {
        if (g == 0) {
            ushort8v o;
#pragma unroll
            for (int j = 0; j < 8; j++) o[j] = f2bfbits(f[j]);
            *reinterpret_cast<ushort8v*>(out_bf + (size_t)node * 64 + t * 8) = o;
        }
    } else {
        if (g == 0) {
            float4 o0 = {f[0], f[1], f[2], f[3]};
            float4 o1 = {f[4], f[5], f[6], f[7]};
            *reinterpret_cast<float4*>(out_h + (size_t)node * 64 + t * 8) = o0;
            *reinterpret_cast<float4*>(out_h + (size_t)node * 64 + t * 8 + 4) = o1;
        }
        float p0 = 0.f, p1 = 0.f;
#pragma unroll
        for (int j = 0; j < 8; j++) {
            p0 += f[j] * Wc[(t * 8 + j) * 2];
            p1 += f[j] * Wc[(t * 8 + j) * 2 + 1];
        }
#pragma unroll
        for (int o = 4; o; o >>= 1) {
            p0 += __shfl_xor(p0, o, 64);
            p1 += __shfl_xor(p1, o, 64);
        }
        if (lane == 0) {
            out_logits[(size_t)node * 2 + 0] = p0 + bc[0];
            out_logits[(size_t)node * 2 + 1] = p1 + bc[1];
        }
    }
}

// ---------------------------------------------------------------------------
extern "C" void kernel_launch(void* const* d_in, const int* in_sizes, int n_in,
                              void* d_out, int out_size, void* d_ws, size_t ws_size,
                              hipStream_t stream) {
    const float* x   = (const float*)d_in[0];
    const int*   ei  = (const int*)d_in[1];
    const float* W1  = (const float*)d_in[2];
    const float* b1  = (const float*)d_in[3];
    const float* W2  = (const float*)d_in[4];
    const float* b2  = (const float*)d_in[5];
    const float* Wg1 = (const float*)d_in[6];
    const float* bg1 = (const float*)d_in[7];
    const float* Wg2 = (const float*)d_in[8];
    const float* bg2 = (const float*)d_in[9];
    const float* Wc  = (const float*)d_in[10];
    const float* bc  = (const float*)d_in[11];

    const int DH  = in_sizes[3];            // 128
    const int DIN = in_sizes[2] / DH;       // 512
    const int NN  = in_sizes[0] / DIN;      // 100000
    const int E   = in_sizes[1] / 2;        // 3200000
    const int DO  = in_sizes[5];            // 64
    const int* src = ei;
    const int* dst = ei + E;

    // workspace layout
    char*  ws  = (char*)d_ws;
    size_t off = 0;
    auto alloc = [&](size_t bytes) {
        void* p = ws + off;
        off += (bytes + 255) & ~(size_t)255;
        return p;
    };
    const int NB = (NN + 255) >> 8;  // 391 buckets
    __hip_bfloat16* h1    = (__hip_bfloat16*)alloc((size_t)NN * DH * 2);
    __hip_bfloat16* h2    = (__hip_bfloat16*)alloc((size_t)NN * DO * 2);
    __hip_bfloat16* h3    = (__hip_bfloat16*)alloc((size_t)NN * DO * 2);
    __hip_bfloat16* ub    = (__hip_bfloat16*)alloc((size_t)NN * DO * 2);
    float*          dinv  = (float*)alloc((size_t)NN * 4);
    uint2*          rp2   = (uint2*)alloc((size_t)NN * 8);
    int*            csr   = (int*)alloc((size_t)NB * BCAP * 4);
    unsigned*       ebuck = (unsigned*)alloc((size_t)NB * BCAP * 4);
    unsigned*       bcur  = (unsigned*)alloc(512 * 4);
    __hip_bfloat16* W1f   = (__hip_bfloat16*)alloc((size_t)DIN * DH * 2);
    __hip_bfloat16* W2t   = (__hip_bfloat16*)alloc((size_t)DH * DO * 2);
    __hip_bfloat16* Wg1t  = (__hip_bfloat16*)alloc((size_t)DO * DO * 2);
    __hip_bfloat16* Wg2t  = (__hip_bfloat16*)alloc((size_t)DO * DO * 2);

    float* out_logits = (float*)d_out;
    float* out_h      = (float*)d_out + (size_t)NN * 2;

    // L1: weight prep + cursor zero (one launch)
    const int fragBlocks  = (DIN * DH + 255) / 256;
    const int smallBlocks = (DH * DO + 2 * DO * DO + 255) / 256;
    const int zeroBlocks  = (NB + 255) / 256;
    prep_all<<<fragBlocks + smallBlocks + zeroBlocks, 256, 0, stream>>>(
        W1, W2, Wg1, Wg2, W1f, W2t, Wg1t, Wg2t, bcur, DIN, DH, DO, NB);

    // L2: bucket_scatter || gemm_enc1 (role-interleaved, enc1 barrier-free)
    const int nblkP = (E + EPB - 1) / EPB;       // 500
    const int enc1B = (NN + 127) / 128;          // 782
    mega_scatter_enc1<<<nblkP + enc1B, 512, 0, stream>>>(
        src, dst, bcur, ebuck, E, NB, nblkP,
        x, (const v8bf16*)W1f, b1, h1, NN);

    // L3: bucket_csr || gemm_enc2 (role-interleaved)
    const int gemm_blocks = (NN / 16 + 3) / 4;   // 1563
    mega_csr_enc2<<<NB + gemm_blocks, 256, 0, stream>>>(
        bcur, ebuck, rp2, dinv, csr, NN, NB,
        h1, W2t, b2, h2, NN, DH);

    // L4: GCN layer 1 linear: ub = (h2@Wg1)*dinv
    gemm_kernel<4, 1><<<gemm_blocks, 256, 0, stream>>>(h2, Wg1t, nullptr, dinv, ub, NN, DO);
    // L5: gather + epilogue -> h3 (bf16)
    gather_kernel<0><<<(NN + 3) / 4, 256, 0, stream>>>(rp2, csr, ub, dinv, bg1, h3,
                                                       nullptr, nullptr, nullptr, nullptr, NN);

    // L6: GCN layer 2 linear
    gemm_kernel<4, 1><<<gemm_blocks, 256, 0, stream>>>(h3, Wg2t, nullptr, dinv, ub, NN, DO);
    // L7: gather + head
    gather_kernel<1><<<(NN + 3) / 4, 256, 0, stream>>>(rp2, csr, ub, dinv, bg2, nullptr,
                                                       out_h, Wc, bc, out_logits, NN);
}

// Round 6
// 544.240 us; speedup vs baseline: 1.0959x; 1.0959x over previous
//
#include <hip/hip_runtime.h>
#include <hip/hip_bf16.h>

typedef __bf16 v8bf16 __attribute__((ext_vector_type(8)));
typedef float  v4f32  __attribute__((ext_vector_type(4)));
typedef unsigned short ushort8v __attribute__((ext_vector_type(8)));

static __device__ __forceinline__ float leaky(float v) { return v >= 0.0f ? v : 0.01f * v; }
static __device__ __forceinline__ float bfbits2f(unsigned short b) {
    union { unsigned u; float f; } c; c.u = ((unsigned)b) << 16; return c.f;
}
static __device__ __forceinline__ unsigned short f2bfbits(float f) {
    __hip_bfloat16 h = __float2bfloat16(f);
    unsigned short s; __builtin_memcpy(&s, &h, 2); return s;
}

// ---------------------------------------------------------------------------
// CSR build constants: buckets of 256 dst nodes, fixed-capacity padded
// regions (mean load 8184, BCAP=16384 ~ 90 sigma for uniform random dst).
// ebuck word: src | (dst&255)<<20  (needs NN < 2^20).
// csr uses the SAME padded layout (bucket k at k*BCAP) -> no global scan.
// ---------------------------------------------------------------------------
constexpr int EPB  = 6400;
constexpr int BCAP = 16384;

// Proportional interleave: spread nA "A-role" blocks uniformly over tot bids
// so each CU's resident set mixes latency-bound and MFMA blocks.
static __device__ __forceinline__ bool role_split(int bid, int nA, int tot,
                                                  int& idxA, int& idxB) {
    const long long s0 = (long long)bid * nA / tot;
    const long long s1 = (long long)(bid + 1) * nA / tot;
    if (s1 > s0) { idxA = (int)s0; idxB = 0; return true; }
    idxA = 0; idxB = bid - (int)s0; return false;
}

// ---------------------------------------------------------------------------
// L1: fused weight prep + bcur zero.
// ---------------------------------------------------------------------------
__global__ __launch_bounds__(256) void prep_all(
    const float* __restrict__ W1, const float* __restrict__ W2,
    const float* __restrict__ Wg1, const float* __restrict__ Wg2,
    __hip_bfloat16* __restrict__ W1f, __hip_bfloat16* __restrict__ W2t,
    __hip_bfloat16* __restrict__ Wg1t, __hip_bfloat16* __restrict__ Wg2t,
    unsigned* __restrict__ bcur, int DIN, int DH, int DO, int NB) {
    const int fragTotal  = DIN * DH;
    const int fragBlocks = (fragTotal + 255) / 256;
    const int n2 = DH * DO, ng = DO * DO;
    const int smallTotal  = n2 + 2 * ng;
    const int smallBlocks = (smallTotal + 255) / 256;
    const int bid = blockIdx.x;
    if (bid < fragBlocks) {
        int tid = bid * 256 + threadIdx.x;
        if (tid >= fragTotal) return;
        int j = tid & 7, l = (tid >> 3) & 63, G = tid >> 9;
        int m = l & 15, q = l >> 4;
        int t = G & 7, kk = G >> 3;
        int n = t * 16 + m;
        int k = kk * 32 + q * 8 + j;
        W1f[tid] = __float2bfloat16(W1[k * DH + n]);
    } else if (bid < fragBlocks + smallBlocks) {
        int i = (bid - fragBlocks) * 256 + threadIdx.x;
        if (i < n2) {
            int r = i / DO, c = i % DO;
            W2t[c * DH + r] = __float2bfloat16(W2[i]);
        } else if (i < n2 + ng) {
            int j = i - n2; int r = j / DO, c = j % DO;
            Wg1t[c * DO + r] = __float2bfloat16(Wg1[j]);
        } else if (i < smallTotal) {
            int j = i - n2 - ng; int r = j / DO, c = j % DO;
            Wg2t[c * DO + r] = __float2bfloat16(Wg2[j]);
        }
    } else {
        int i = (bid - fragBlocks - smallBlocks) * 256 + threadIdx.x;
        if (i < NB) bcur[i] = 0u;
    }
}

// ---------------------------------------------------------------------------
// Scatter body (512 threads): partition edges into per-bucket regions.
// dst values held in registers between phases (one global read of dst).
// ---------------------------------------------------------------------------
struct ScatterSmem {
    unsigned stg[EPB];
    unsigned hist[512], inc[512], cur[512], start[512];
};

static __device__ __forceinline__ void scatter_body(
    int bid, ScatterSmem& sm, const int* __restrict__ src, const int* __restrict__ dst,
    unsigned* __restrict__ bcur, unsigned* __restrict__ ebuck, int E, int NB) {
    const int tid = threadIdx.x;
    sm.hist[tid] = 0u;
    __syncthreads();
    const int beg = bid * EPB;
    const int end = min(beg + EPB, E);
    unsigned myd[13];
#pragma unroll
    for (int i = 0; i < 13; i++) {
        const int e = beg + tid + i * 512;
        if (e < end) {
            const unsigned d = (unsigned)dst[e];
            myd[i] = d;
            atomicAdd(&sm.hist[d >> 8], 1u);
        }
    }
    __syncthreads();
    const unsigned h = sm.hist[tid];
    sm.inc[tid] = h;
    __syncthreads();
    for (int off = 1; off < 512; off <<= 1) {
        unsigned t = (tid >= off) ? sm.inc[tid - off] : 0u;
        __syncthreads();
        sm.inc[tid] += t;
        __syncthreads();
    }
    sm.cur[tid] = sm.inc[tid] - h;
    if (tid < NB && h > 0u)
        sm.start[tid] = (unsigned)tid * BCAP + atomicAdd(&bcur[tid], h);
    __syncthreads();
#pragma unroll
    for (int i = 0; i < 13; i++) {
        const int e = beg + tid + i * 512;
        if (e < end) {
            const unsigned b = myd[i] >> 8;
            const unsigned r = atomicAdd(&sm.cur[b], 1u);
            sm.stg[r] = (unsigned)e;
        }
    }
    __syncthreads();
    const int cnt = end - beg;
    for (int s = tid; s < cnt; s += 512) {
        const unsigned e = sm.stg[s];
        const unsigned d = (unsigned)dst[e];   // L1-warm (25.6 KB window)
        const unsigned b = d >> 8;
        const unsigned excl = sm.inc[b] - sm.hist[b];
        const unsigned pos = sm.start[b] + ((unsigned)s - excl);
        ebuck[pos] = (unsigned)src[e] | ((d & 255u) << 20);
    }
}

// ---------------------------------------------------------------------------
// enc1 body (512 threads, 8 waves x 16 rows = 128 rows/block), LDS-staged:
// C[M,128] = leaky(A[M,512]@W1 + b1), A fp32, Bp fragment-ordered bf16.
// ---------------------------------------------------------------------------
static __device__ __forceinline__ void enc1_body(
    int bid, uint4 (*lds)[1024], const float* __restrict__ A, const uint4* __restrict__ Bp,
    const float* __restrict__ bias, __hip_bfloat16* __restrict__ C, int M) {
    constexpr int K = 512;
    const int tid = threadIdx.x;
    const int wid = tid >> 6, lane = tid & 63;
    const int m = lane & 15, q = lane >> 4;
    const int row0 = bid * 128 + wid * 16;
    const int rowA = row0 + m;
    const int rowAc = rowA < M ? rowA : M - 1;
    const float* Ap = A + (size_t)rowAc * K + q * 8;

    v4f32 acc[8];
#pragma unroll
    for (int t = 0; t < 8; t++) acc[t] = (v4f32){0.f, 0.f, 0.f, 0.f};

    float4 ab[2][4];
    auto loadA = [&](int c, int par) {
#pragma unroll
        for (int j = 0; j < 4; j++)
            ab[par][j] = *reinterpret_cast<const float4*>(Ap + c * 64 + (j >> 1) * 32 + (j & 1) * 4);
    };
    auto stage = [&](int c, int par) {
        lds[par][tid]       = Bp[c * 1024 + tid];
        lds[par][512 + tid] = Bp[c * 1024 + 512 + tid];
    };

    stage(0, 0);
    loadA(0, 0);
    for (int c = 0; c < 8; c++) {
        __syncthreads();
        if (c < 7) { stage(c + 1, (c + 1) & 1); loadA(c + 1, (c + 1) & 1); }
        const int par = c & 1;
#pragma unroll
        for (int kk2 = 0; kk2 < 2; kk2++) {
            float4 f0 = ab[par][kk2 * 2], f1 = ab[par][kk2 * 2 + 1];
            v8bf16 a = {(__bf16)f0.x, (__bf16)f0.y, (__bf16)f0.z, (__bf16)f0.w,
                        (__bf16)f1.x, (__bf16)f1.y, (__bf16)f1.z, (__bf16)f1.w};
#pragma unroll
            for (int t = 0; t < 8; t++) {
                v8bf16 b = reinterpret_cast<const v8bf16*>(lds[par])[(kk2 * 8 + t) * 64 + lane];
                acc[t] = __builtin_amdgcn_mfma_f32_16x16x32_bf16(a, b, acc[t], 0, 0, 0);
            }
        }
    }

#pragma unroll
    for (int r = 0; r < 4; r++) {
        const int row = row0 + q * 4 + r;
        if (row >= M) continue;
#pragma unroll
        for (int t = 0; t < 8; t++) {
            const int col = t * 16 + m;
            C[(size_t)row * 128 + col] = __float2bfloat16(leaky(acc[t][r] + bias[col]));
        }
    }
}

// ---------------------------------------------------------------------------
// L2: mega kernel = bucket_scatter || gemm_enc1, role-interleaved.
// ---------------------------------------------------------------------------
__global__ __launch_bounds__(512, 4) void mega_scatter_enc1(
    const int* __restrict__ src, const int* __restrict__ dst,
    unsigned* __restrict__ bcur, unsigned* __restrict__ ebuck, int E, int NB, int nScatter,
    const float* __restrict__ A, const uint4* __restrict__ Bp,
    const float* __restrict__ bias, __hip_bfloat16* __restrict__ C, int M) {
    union Smem {
        ScatterSmem sc;
        uint4 g[2][1024];
    };
    __shared__ Smem sm;
    int ia, ib;
    if (role_split(blockIdx.x, nScatter, gridDim.x, ia, ib))
        scatter_body(ia, sm.sc, src, dst, bcur, ebuck, E, NB);
    else
        enc1_body(ib, sm.g, A, Bp, bias, C, M);
}

// ---------------------------------------------------------------------------
// Small GEMM body (bf16 A): C[M,N] = A[M,K]@B, Bt[N][K] bf16.
// MODE 0: C=bf16(leaky(AB+bias));  MODE 1: C=bf16((AB)*dinv[row])
// ---------------------------------------------------------------------------
template <int NT, int MODE>
static __device__ __forceinline__ void gemm_body(
    int bid, const __hip_bfloat16* __restrict__ A, const __hip_bfloat16* __restrict__ Bt,
    const float* __restrict__ bias, const float* __restrict__ dinv,
    __hip_bfloat16* __restrict__ Cbf, int M, int K) {
    const int wid  = threadIdx.x >> 6;
    const int lane = threadIdx.x & 63;
    const int row0 = (bid * 4 + wid) << 4;
    if (row0 >= M) return;
    const int m = lane & 15, q = lane >> 4;

    const __hip_bfloat16* Ab = A + (size_t)(row0 + m) * K + q * 8;

    v4f32 acc[NT];
#pragma unroll
    for (int t = 0; t < NT; t++) acc[t] = (v4f32){0.f, 0.f, 0.f, 0.f};

    for (int k0 = 0; k0 < K; k0 += 32) {
        v8bf16 a = *reinterpret_cast<const v8bf16*>(Ab + k0);
#pragma unroll
        for (int t = 0; t < NT; t++) {
            v8bf16 b = *reinterpret_cast<const v8bf16*>(Bt + (size_t)(t * 16 + m) * K + k0 + q * 8);
            acc[t] = __builtin_amdgcn_mfma_f32_16x16x32_bf16(a, b, acc[t], 0, 0, 0);
        }
    }

    const int N = NT * 16;
#pragma unroll
    for (int r = 0; r < 4; r++) {
        const int row = row0 + q * 4 + r;
        float di = (MODE == 1) ? dinv[row] : 1.0f;
#pragma unroll
        for (int t = 0; t < NT; t++) {
            const int col = t * 16 + m;
            float v = acc[t][r];
            if (MODE == 0) v = leaky(v + bias[col]);
            else           v *= di;
            Cbf[(size_t)row * N + col] = __float2bfloat16(v);
        }
    }
}

template <int NT, int MODE>
__global__ __launch_bounds__(256) void gemm_kernel(
    const __hip_bfloat16* __restrict__ A, const __hip_bfloat16* __restrict__ Bt,
    const float* __restrict__ bias, const float* __restrict__ dinv,
    __hip_bfloat16* __restrict__ Cbf, int M, int K) {
    gemm_body<NT, MODE>(blockIdx.x, A, Bt, bias, dinv, Cbf, M, K);
}

// ---------------------------------------------------------------------------
// bucket_csr body: one block per bucket; padded CSR layout (no scan).
// ---------------------------------------------------------------------------
static __device__ __forceinline__ void csr_body(
    int k, unsigned* hist, unsigned* cur, const unsigned* __restrict__ bcur,
    const unsigned* __restrict__ ebuck, uint2* __restrict__ rp2,
    float* __restrict__ dinv, int* __restrict__ csr, int NN) {
    const int tid = threadIdx.x;
    const unsigned cntb = bcur[k];
    const unsigned base = (unsigned)k * BCAP;
    const unsigned* eb = ebuck + base;
    hist[tid] = 0u;
    __syncthreads();
    for (unsigned e = tid; e < cntb; e += 256)
        atomicAdd(&hist[eb[e] >> 20], 1u);
    __syncthreads();
    const unsigned h = hist[tid];
    cur[tid] = h;
    __syncthreads();
    for (int off = 1; off < 256; off <<= 1) {
        unsigned t = (tid >= off) ? cur[tid - off] : 0u;
        __syncthreads();
        cur[tid] += t;
        __syncthreads();
    }
    const unsigned excl = cur[tid] - h;
    const int node = k * 256 + tid;
    if (node < NN) {
        rp2[node] = make_uint2(base + excl, base + excl + h);
        dinv[node] = rsqrtf((float)(h + 1u));  // +1 self-loop
    }
    __syncthreads();
    cur[tid] = excl;
    __syncthreads();
    for (unsigned e = tid; e < cntb; e += 256) {
        const unsigned pk = eb[e];
        const unsigned pos = base + atomicAdd(&cur[pk >> 20], 1u);
        csr[pos] = (int)(pk & 0xFFFFFu);
    }
}

// ---------------------------------------------------------------------------
// L3: mega kernel = bucket_csr || gemm_enc2, role-interleaved.
// ---------------------------------------------------------------------------
__global__ __launch_bounds__(256) void mega_csr_enc2(
    const unsigned* __restrict__ bcur, const unsigned* __restrict__ ebuck,
    uint2* __restrict__ rp2, float* __restrict__ dinv, int* __restrict__ csr,
    int NN, int nCsr,
    const __hip_bfloat16* __restrict__ A, const __hip_bfloat16* __restrict__ Bt,
    const float* __restrict__ bias, __hip_bfloat16* __restrict__ Cb, int M, int K) {
    __shared__ unsigned hist[256], cur[256];
    int ia, ib;
    if (role_split(blockIdx.x, nCsr, gridDim.x, ia, ib))
        csr_body(ia, hist, cur, bcur, ebuck, rp2, dinv, csr, NN);
    else
        gemm_body<4, 0>(ib, A, Bt, bias, nullptr, Cb, M, K);
}

// ---------------------------------------------------------------------------
// Fused CSR gather + GCN epilogue. One wave per dst node.
// 8 groups x 8 lanes; 4-stage software pipeline: 32 rows + 4 index loads in
// flight per wave (avg degree 32 -> typical node = ONE exposed-latency round).
// ---------------------------------------------------------------------------
template <int HEAD>
__global__ __launch_bounds__(256) void gather_kernel(
    const uint2* __restrict__ rp2, const int* __restrict__ csr_src,
    const __hip_bfloat16* __restrict__ u, const float* __restrict__ dinv,
    const float* __restrict__ bias, __hip_bfloat16* __restrict__ out_bf,
    float* __restrict__ out_h, const float* __restrict__ Wc,
    const float* __restrict__ bc, float* __restrict__ out_logits, int n) {
    const int node = blockIdx.x * 4 + (threadIdx.x >> 6);
    if (node >= n) return;
    const int lane = threadIdx.x & 63;
    const int g = lane >> 3, t = lane & 7;  // 8 groups x 8 lanes
    const uint2 rp = rp2[node];
    const unsigned beg = rp.x, end = rp.y;

    float s[8];
#pragma unroll
    for (int j = 0; j < 8; j++) s[j] = 0.f;

    unsigned e = beg + g;
    bool hv[4];
    int idx[4];
#pragma unroll
    for (int p = 0; p < 4; p++) {
        const unsigned ep = e + 8u * p;
        hv[p] = ep < end;
        idx[p] = hv[p] ? csr_src[ep] : 0;
    }
    while (hv[0]) {
        // prefetch next batch's indices
        bool nhv[4];
        int nidx[4];
#pragma unroll
        for (int p = 0; p < 4; p++) {
            const unsigned ep = e + 32u + 8u * p;
            nhv[p] = ep < end;
            nidx[p] = nhv[p] ? csr_src[ep] : 0;
        }
        // issue all row loads, then accumulate
        ushort8v w[4];
#pragma unroll
        for (int p = 0; p < 4; p++)
            if (hv[p]) w[p] = *reinterpret_cast<const ushort8v*>(u + (size_t)idx[p] * 64 + t * 8);
#pragma unroll
        for (int p = 0; p < 4; p++)
            if (hv[p]) {
#pragma unroll
                for (int j = 0; j < 8; j++) s[j] += bfbits2f(w[p][j]);
            }
        e += 32u;
#pragma unroll
        for (int p = 0; p < 4; p++) { hv[p] = nhv[p]; idx[p] = nidx[p]; }
    }
    // reduce across the 8 groups (lane bits 3,4,5)
#pragma unroll
    for (int j = 0; j < 8; j++) {
        s[j] += __shfl_xor(s[j], 8, 64);
        s[j] += __shfl_xor(s[j], 16, 64);
        s[j] += __shfl_xor(s[j], 32, 64);
    }

    // self-loop row
    ushort8v wsr = *reinterpret_cast<const ushort8v*>(u + (size_t)node * 64 + t * 8);
#pragma unroll
    for (int j = 0; j < 8; j++) s[j] += bfbits2f(wsr[j]);

    const float di = dinv[node];
    const float4 b0 = *reinterpret_cast<const float4*>(bias + t * 8);
    const float4 b1 = *reinterpret_cast<const float4*>(bias + t * 8 + 4);
    float f[8];
    f[0] = leaky(s[0] * di + b0.x); f[1] = leaky(s[1] * di + b0.y);
    f[2] = leaky(s[2] * di + b0.z); f[3] = leaky(s[3] * di + b0.w);
    f[4] = leaky(s[4] * di + b1.x); f[5] = leaky(s[5] * di + b1.y);
    f[6] = leaky(s[6] * di + b1.z); f[7] = leaky(s[7] * di + b1.w);

    if (HEAD == 0) {
        if (g == 0) {
            ushort8v o;
#pragma unroll
            for (int j = 0; j < 8; j++) o[j] = f2bfbits(f[j]);
            *reinterpret_cast<ushort8v*>(out_bf + (size_t)node * 64 + t * 8) = o;
        }
    } else {
        if (g == 0) {
            float4 o0 = {f[0], f[1], f[2], f[3]};
            float4 o1 = {f[4], f[5], f[6], f[7]};
            *reinterpret_cast<float4*>(out_h + (size_t)node * 64 + t * 8) = o0;
            *reinterpret_cast<float4*>(out_h + (size_t)node * 64 + t * 8 + 4) = o1;
        }
        float p0 = 0.f, p1 = 0.f;
#pragma unroll
        for (int j = 0; j < 8; j++) {
            p0 += f[j] * Wc[(t * 8 + j) * 2];
            p1 += f[j] * Wc[(t * 8 + j) * 2 + 1];
        }
#pragma unroll
        for (int o = 4; o; o >>= 1) {
            p0 += __shfl_xor(p0, o, 64);
            p1 += __shfl_xor(p1, o, 64);
        }
        if (lane == 0) {
            out_logits[(size_t)node * 2 + 0] = p0 + bc[0];
            out_logits[(size_t)node * 2 + 1] = p1 + bc[1];
        }
    }
}

// ---------------------------------------------------------------------------
extern "C" void kernel_launch(void* const* d_in, const int* in_sizes, int n_in,
                              void* d_out, int out_size, void* d_ws, size_t ws_size,
                              hipStream_t stream) {
    const float* x   = (const float*)d_in[0];
    const int*   ei  = (const int*)d_in[1];
    const float* W1  = (const float*)d_in[2];
    const float* b1  = (const float*)d_in[3];
    const float* W2  = (const float*)d_in[4];
    const float* b2  = (const float*)d_in[5];
    const float* Wg1 = (const float*)d_in[6];
    const float* bg1 = (const float*)d_in[7];
    const float* Wg2 = (const float*)d_in[8];
    const float* bg2 = (const float*)d_in[9];
    const float* Wc  = (const float*)d_in[10];
    const float* bc  = (const float*)d_in[11];

    const int DH  = in_sizes[3];            // 128
    const int DIN = in_sizes[2] / DH;       // 512
    const int NN  = in_sizes[0] / DIN;      // 100000
    const int E   = in_sizes[1] / 2;        // 3200000
    const int DO  = in_sizes[5];            // 64
    const int* src = ei;
    const int* dst = ei + E;

    // workspace layout
    char*  ws  = (char*)d_ws;
    size_t off = 0;
    auto alloc = [&](size_t bytes) {
        void* p = ws + off;
        off += (bytes + 255) & ~(size_t)255;
        return p;
    };
    const int NB = (NN + 255) >> 8;  // 391 buckets
    __hip_bfloat16* h1    = (__hip_bfloat16*)alloc((size_t)NN * DH * 2);
    __hip_bfloat16* h2    = (__hip_bfloat16*)alloc((size_t)NN * DO * 2);
    __hip_bfloat16* h3    = (__hip_bfloat16*)alloc((size_t)NN * DO * 2);
    __hip_bfloat16* ub    = (__hip_bfloat16*)alloc((size_t)NN * DO * 2);
    float*          dinv  = (float*)alloc((size_t)NN * 4);
    uint2*          rp2   = (uint2*)alloc((size_t)NN * 8);
    int*            csr   = (int*)alloc((size_t)NB * BCAP * 4);
    unsigned*       ebuck = (unsigned*)alloc((size_t)NB * BCAP * 4);
    unsigned*       bcur  = (unsigned*)alloc(512 * 4);
    __hip_bfloat16* W1f   = (__hip_bfloat16*)alloc((size_t)DIN * DH * 2);
    __hip_bfloat16* W2t   = (__hip_bfloat16*)alloc((size_t)DH * DO * 2);
    __hip_bfloat16* Wg1t  = (__hip_bfloat16*)alloc((size_t)DO * DO * 2);
    __hip_bfloat16* Wg2t  = (__hip_bfloat16*)alloc((size_t)DO * DO * 2);

    float* out_logits = (float*)d_out;
    float* out_h      = (float*)d_out + (size_t)NN * 2;

    // L1: weight prep + cursor zero (one launch)
    const int fragBlocks  = (DIN * DH + 255) / 256;
    const int smallBlocks = (DH * DO + 2 * DO * DO + 255) / 256;
    const int zeroBlocks  = (NB + 255) / 256;
    prep_all<<<fragBlocks + smallBlocks + zeroBlocks, 256, 0, stream>>>(
        W1, W2, Wg1, Wg2, W1f, W2t, Wg1t, Wg2t, bcur, DIN, DH, DO, NB);

    // L2: bucket_scatter || gemm_enc1 (role-interleaved, LDS-staged enc1)
    const int nblkP = (E + EPB - 1) / EPB;       // 500
    const int enc1B = (NN + 127) / 128;          // 782
    mega_scatter_enc1<<<nblkP + enc1B, 512, 0, stream>>>(
        src, dst, bcur, ebuck, E, NB, nblkP,
        x, (const uint4*)W1f, b1, h1, NN);

    // L3: bucket_csr || gemm_enc2 (role-interleaved)
    const int gemm_blocks = (NN / 16 + 3) / 4;   // 1563
    mega_csr_enc2<<<NB + gemm_blocks, 256, 0, stream>>>(
        bcur, ebuck, rp2, dinv, csr, NN, NB,
        h1, W2t, b2, h2, NN, DH);

    // L4: GCN layer 1 linear: ub = (h2@Wg1)*dinv
    gemm_kernel<4, 1><<<gemm_blocks, 256, 0, stream>>>(h2, Wg1t, nullptr, dinv, ub, NN, DO);
    // L5: gather + epilogue -> h3 (bf16)
    gather_kernel<0><<<(NN + 3) / 4, 256, 0, stream>>>(rp2, csr, ub, dinv, bg1, h3,
                                                       nullptr, nullptr, nullptr, nullptr, NN);

    // L6: GCN layer 2 linear
    gemm_kernel<4, 1><<<gemm_blocks, 256, 0, stream>>>(h3, Wg2t, nullptr, dinv, ub, NN, DO);
    // L7: gather + head
    gather_kernel<1><<<(NN + 3) / 4, 256, 0, stream>>>(rp2, csr, ub, dinv, bg2, nullptr,
                                                       out_h, Wc, bc, out_logits, NN);
}